// Round 12
// baseline (360.561 us; speedup 1.0000x reference)
//
#include <hip/hip_runtime.h>

#define N_TOKENS 131072
#define DIM 64
#define N_EMBED 1024
#define DECAYF 0.99f
#define OMDF 0.01f
#define EPSF 1e-5f
#define SUM_TPB 128   // tokens per block in vq_sum (4 waves x 32)

#define TOK_TILE 128
#define CODE_CHUNK 128
#define NCHUNK (N_EMBED / CODE_CHUNK)
#define APAD 68       // 64 + 4 floats: bank shift 4/row, keeps 16B alignment
#define BPAD 36       // 32 + 4 floats (k-half rows)

// Output layout (floats), reference return order:
// quantize_st [131072*64], diff [1], embed_ind [131072], new_embed [64*1024],
// new_cluster_size [1024], new_embed_avg [64*1024]
#define OFF_QST  ((size_t)0)
#define OFF_DIFF ((size_t)8388608)
#define OFF_IND  ((size_t)8388609)
#define OFF_NE   ((size_t)8519681)
#define OFF_NCS  ((size_t)8585217)
#define OFF_NEA  ((size_t)8586241)

// ws layout: floats then ints
// f[0] diff_sum, f[1] n_val, f[1026..66562) es, f[66562..132098) embedT,
// f[132098..133122) cnorm; ints at f-index 133632:
// cnt_i[1024], start_i[1024], cursor_i[1024], sorted[131072], scode[131072]
#define WS_DIFF   0
#define WS_NVAL   1
#define WS_ES     1026
#define WS_ET     66562
#define WS_CNORM  132098
#define WS_IWS    133632

// Fused prep: blocks 0..255 transpose embed -> embedT; blocks 256..259 compute
// code norms straight from the original [d][e] layout (lane-consecutive ->
// coalesced); block 260 zeroes the accumulators (replaces 2 memsets).
__global__ __launch_bounds__(256) void vq_prep(
    const float* __restrict__ embed, float* __restrict__ embedT,
    float* __restrict__ cnorm, float* __restrict__ diff_sum,
    int* __restrict__ cnt_i)
{
    const int b = blockIdx.x, t = threadIdx.x;
    if (b < 256) {
        int i = b * 256 + t;
        int d = i >> 10, e = i & 1023;
        embedT[e * DIM + d] = embed[i];
    } else if (b < 260) {
        int e = (b - 256) * 256 + t;
        float s = 0.f;
#pragma unroll
        for (int d = 0; d < DIM; ++d) {
            float v = embed[d * N_EMBED + e];
            s = fmaf(v, v, s);
        }
        cnorm[e] = s;
    } else {
        for (int i = t; i < N_EMBED; i += 256) cnt_i[i] = 0;
        if (t < 2) diff_sum[t] = 0.f;      // diff_sum, n_val
    }
}

// Register-tiled distance GEMM + fused argmin.
// Block tile: 128 tokens x 128 codes. 4 waves as 2x2; wave tile 64x64;
// lane grid 8x8; 8x8 acc/thread. ks loop unroll-1 (r8 spill fix); scalarized
// pv0..3 register prefetch (r11 alloca fix).
// r12: ecs double-buffered -> ONE barrier per (chunk,kh) phase (16 vs 32).
// Safety: phase-p write to ecs[p&1] races only with phase-(p-2) reads, which
// all waves finished before arriving at barrier p-1. cnc LDS buffer removed:
// per-thread code norms pcn0..7 prefetched from global (L2-hot 4KB) at chunk
// top, consumed a full ~6000-cyc chunk later.
__global__ __launch_bounds__(256, 1) void vq_main(
    const float* __restrict__ x, const float* __restrict__ embedT,
    const float* __restrict__ cnorm, float* __restrict__ out,
    float* __restrict__ diff_sum, int* __restrict__ cnt_i)
{
    __shared__ float xs[TOK_TILE * APAD];       // 34816 B
    __shared__ float ecs[2][CODE_CHUNK * BPAD]; // 2 x 18432 B
    __shared__ int   lhist[N_EMBED];            // 4096 B
    __shared__ float red_d[2 * TOK_TILE];
    __shared__ int   red_i[2 * TOK_TILE];
    __shared__ int   bi_l[TOK_TILE];            // total 78336 B -> 2 blocks/CU

    const int t = threadIdx.x;
    const int w = t >> 6, lane = t & 63;
    const int wr = w >> 1, wc = w & 1;
    const int r = lane >> 3, c = lane & 7;
    const int bc = t >> 3;                      // staging base code (0..31)
    const int kk = (t & 7) << 2;                // staging k offset (floats)

    for (int i = t; i < N_EMBED; i += 256) lhist[i] = 0;

    // stage A: 128 x rows -> padded LDS rows (2048 float4 / 256 thr = 8 each)
    {
        const float4* xsrc = (const float4*)(x + (size_t)blockIdx.x * TOK_TILE * DIM);
#pragma unroll
        for (int j = 0; j < 8; ++j) {
            int g = j * 256 + t;
            int tok = g >> 4, kx = (g & 15) << 2;
            float4 v = xsrc[g];
            *(float4*)(xs + tok * APAD + kx) = v;
        }
    }

    float best[8];
    int   bidx[8];
#pragma unroll
    for (int i = 0; i < 8; ++i) { best[i] = 3.4e38f; bidx[i] = 0; }

    // staging-prefetch registers (named scalars -> guaranteed VGPRs)
    float4 pv0, pv1, pv2, pv3;
    {   // prologue: prefetch phase 0 = (chunk0, kh0)
        const float* pbase = embedT + kk;
        pv0 = *(const float4*)(pbase + (size_t)(bc) * DIM);
        pv1 = *(const float4*)(pbase + (size_t)(32 + bc) * DIM);
        pv2 = *(const float4*)(pbase + (size_t)(64 + bc) * DIM);
        pv3 = *(const float4*)(pbase + (size_t)(96 + bc) * DIM);
    }

    for (int chunk = 0; chunk < NCHUNK; ++chunk) {
        // per-thread code-norm prefetch for this chunk's argmin (named scalars)
        const float* cnb = cnorm + chunk * CODE_CHUNK + wc * 64 + c;
        float pcn0 = cnb[0],  pcn1 = cnb[8],  pcn2 = cnb[16], pcn3 = cnb[24];
        float pcn4 = cnb[32], pcn5 = cnb[40], pcn6 = cnb[48], pcn7 = cnb[56];

        float acc[8][8];
#pragma unroll
        for (int i = 0; i < 8; ++i)
#pragma unroll
            for (int j = 0; j < 8; ++j) acc[i][j] = 0.f;

#pragma unroll
        for (int kh = 0; kh < 2; ++kh) {
            const int p = chunk * 2 + kh;
            float* eb = ecs[p & 1];
            // commit prefetched k-half to this phase's buffer
            *(float4*)(eb + (bc) * BPAD + kk)      = pv0;
            *(float4*)(eb + (32 + bc) * BPAD + kk) = pv1;
            *(float4*)(eb + (64 + bc) * BPAD + kk) = pv2;
            *(float4*)(eb + (96 + bc) * BPAD + kk) = pv3;
            {   // issue prefetch for next phase (last phase reloads itself)
                int idx = p + 1;
                int nc = (idx < 2 * NCHUNK) ? (idx >> 1) : (NCHUNK - 1);
                int nk = idx & 1;
                const float* pbase = embedT + (size_t)nc * CODE_CHUNK * DIM
                                   + nk * 32 + kk;
                pv0 = *(const float4*)(pbase + (size_t)(bc) * DIM);
                pv1 = *(const float4*)(pbase + (size_t)(32 + bc) * DIM);
                pv2 = *(const float4*)(pbase + (size_t)(64 + bc) * DIM);
                pv3 = *(const float4*)(pbase + (size_t)(96 + bc) * DIM);
            }
            __syncthreads();   // single barrier per phase (dbuf)

            const float* xbase = xs + (wr * 64) * APAD + kh * 32;
            const float* bbase = eb + (wc * 64) * BPAD;
#pragma unroll 1
            for (int ks = 0; ks < 8; ++ks) {
                float4 a4[8];
#pragma unroll
                for (int i = 0; i < 8; ++i)
                    a4[i] = *(const float4*)(xbase + (r + 8 * i) * APAD + ks * 4);
#pragma unroll
                for (int j = 0; j < 8; ++j) {
                    float4 b4 = *(const float4*)(bbase + (c + 8 * j) * BPAD + ks * 4);
#pragma unroll
                    for (int i = 0; i < 8; ++i) {
                        acc[i][j] = fmaf(a4[i].x, b4.x, acc[i][j]);
                        acc[i][j] = fmaf(a4[i].y, b4.y, acc[i][j]);
                        acc[i][j] = fmaf(a4[i].z, b4.z, acc[i][j]);
                        acc[i][j] = fmaf(a4[i].w, b4.w, acc[i][j]);
                    }
                }
            }
        }

        // dists + running argmin (codes ascending: strict < = first-index ties)
#define ARGMIN_COL(J, PCN)                                                   \
        {                                                                    \
            int gcode = chunk * CODE_CHUNK + wc * 64 + c + 8 * J;            \
            _Pragma("unroll")                                                \
            for (int i = 0; i < 8; ++i) {                                    \
                float dist = fmaf(-2.f, acc[i][J], PCN);                     \
                if (dist < best[i]) { best[i] = dist; bidx[i] = gcode; }     \
            }                                                                \
        }
        ARGMIN_COL(0, pcn0) ARGMIN_COL(1, pcn1) ARGMIN_COL(2, pcn2)
        ARGMIN_COL(3, pcn3) ARGMIN_COL(4, pcn4) ARGMIN_COL(5, pcn5)
        ARGMIN_COL(6, pcn6) ARGMIN_COL(7, pcn7)
#undef ARGMIN_COL
    }

    // reduce over lane columns (c bits = lane bits 0..2)
#pragma unroll
    for (int i = 0; i < 8; ++i) {
        float d = best[i]; int bi = bidx[i];
#pragma unroll
        for (int m = 1; m < 8; m <<= 1) {
            float d2 = __shfl_xor(d, m, 64);
            int   i2 = __shfl_xor(bi, m, 64);
            if (d2 < d || (d2 == d && i2 < bi)) { d = d2; bi = i2; }
        }
        if (c == 0) {
            int tok = wr * 64 + r + 8 * i;
            red_d[wc * TOK_TILE + tok] = d;
            red_i[wc * TOK_TILE + tok] = bi;
        }
    }
    __syncthreads();

    if (t < TOK_TILE) {
        float d0 = red_d[t];            int i0 = red_i[t];
        float d1 = red_d[TOK_TILE + t]; int i1 = red_i[TOK_TILE + t];
        int bi = (d1 < d0 || (d1 == d0 && i1 < i0)) ? i1 : i0;
        bi_l[t] = bi;
        out[OFF_IND + (size_t)blockIdx.x * TOK_TILE + t] = (float)bi;
        atomicAdd(&lhist[bi], 1);
    }
    __syncthreads();

    // quantize write (coalesced) + diff partials
    float ds = 0.f;
    {
        const float4* et4 = (const float4*)embedT;
        float4* qst = (float4*)(out + OFF_QST + (size_t)blockIdx.x * TOK_TILE * DIM);
#pragma unroll
        for (int j = 0; j < 8; ++j) {
            int g = j * 256 + t;
            int tok = g >> 4, f = g & 15;
            int bi = bi_l[tok];
            float4 q = et4[bi * 16 + f];
            float4 xv = *(const float4*)(xs + tok * APAD + (f << 2));
            qst[g] = q;                                // x + stopgrad(q-x) == q
            float ex = q.x - xv.x, ey = q.y - xv.y, ez = q.z - xv.z, ew = q.w - xv.w;
            ds = fmaf(ex, ex, ds); ds = fmaf(ey, ey, ds);
            ds = fmaf(ez, ez, ds); ds = fmaf(ew, ew, ds);
        }
    }
#pragma unroll
    for (int o = 32; o > 0; o >>= 1) ds += __shfl_down(ds, o, 64);
    if (lane == 0) atomicAdd(diff_sum, ds);

    // flush histogram
    for (int i = t; i < N_EMBED; i += 256) {
        int cv = lhist[i];
        if (cv) atomicAdd(&cnt_i[i], cv);
    }
}

// single block, 1024 threads: exclusive prefix over cnt_i -> cursor_i,
// PLUS (merged former vq_final1) EMA cluster size, n, diff finalize.
__global__ __launch_bounds__(1024) void vq_start(
    const int* __restrict__ cnt_i, int* __restrict__ cursor_i,
    const float* __restrict__ cluster_size, const float* __restrict__ diff_sum,
    float* __restrict__ out, float* __restrict__ n_val)
{
    __shared__ int sc[N_EMBED];
    __shared__ float red[16];
    int e = threadIdx.x;
    int c = cnt_i[e];
    sc[e] = c;

    float ncs = cluster_size[e] * DECAYF + OMDF * (float)c;
    out[OFF_NCS + e] = ncs;
    float s = ncs;
#pragma unroll
    for (int o = 32; o > 0; o >>= 1) s += __shfl_down(s, o, 64);
    if ((e & 63) == 0) red[e >> 6] = s;
    __syncthreads();

#pragma unroll
    for (int off = 1; off < N_EMBED; off <<= 1) {
        int v = (e >= off) ? sc[e - off] : 0;
        __syncthreads();
        sc[e] += v;
        __syncthreads();
    }
    cursor_i[e] = sc[e] - c;

    if (e == 0) {
        float nsum = 0.f;
#pragma unroll
        for (int i = 0; i < 16; ++i) nsum += red[i];
        *n_val = nsum;
        out[OFF_DIFF] = *diff_sum / (float)((size_t)N_TOKENS * DIM);
    }
}

// 512 blocks x 256: bin token ids (and their code) into sorted[]/scode[].
// Blocks 0..255 also zero es (replaces a 256 KB memset dispatch).
__global__ __launch_bounds__(256) void vq_sort(
    const float* __restrict__ out, int* __restrict__ cursor_i,
    int* __restrict__ sorted, int* __restrict__ scode,
    float* __restrict__ es)
{
    __shared__ int lh[N_EMBED];
    __shared__ int lbase[N_EMBED];
    int t = threadIdx.x;
    if (blockIdx.x < 256) es[blockIdx.x * 256 + t] = 0.f;
    for (int i = t; i < N_EMBED; i += 256) lh[i] = 0;
    __syncthreads();
    int tok = blockIdx.x * 256 + t;
    int e = (int)out[OFF_IND + tok];                  // exact small ints in float
    int p = atomicAdd(&lh[e], 1);                     // within-block rank (LDS)
    __syncthreads();
    for (int i = t; i < N_EMBED; i += 256) {
        int c = lh[i];
        if (c) lbase[i] = atomicAdd(&cursor_i[i], c); // reserve [base, base+c)
    }
    __syncthreads();
    int pos = lbase[e] + p;
    sorted[pos] = tok;
    scode[pos] = e;
}

// Token-balanced segment sum: 1024 blocks x 128 tokens. Wave lane = dim.
__global__ __launch_bounds__(256) void vq_sum(
    const float* __restrict__ x, const int* __restrict__ sorted,
    const int* __restrict__ scode, float* __restrict__ es)
{
    __shared__ int ltok[SUM_TPB];
    __shared__ int lcode[SUM_TPB];
    const int t = threadIdx.x;
    const int base = blockIdx.x * SUM_TPB;
    if (t < SUM_TPB) {
        ltok[t]  = sorted[base + t];
        lcode[t] = scode[base + t];
    }
    __syncthreads();

    const int w = t >> 6, d = t & 63;
    const int i0 = w * (SUM_TPB / 4);                 // 32 tokens per wave
    int   cur = lcode[i0];
    float acc = 0.f;
#pragma unroll 4
    for (int i = i0; i < i0 + SUM_TPB / 4; ++i) {
        int e = lcode[i];                             // wave-uniform
        if (e != cur) {                               // uniform branch
            atomicAdd(&es[(size_t)cur * DIM + d], acc);
            acc = 0.f;
            cur = e;
        }
        acc += x[(size_t)ltok[i] * DIM + d];          // 256B coalesced row read
    }
    atomicAdd(&es[(size_t)cur * DIM + d], acc);
}

__global__ __launch_bounds__(256) void vq_final2(
    const float* __restrict__ embed_avg, const float* __restrict__ es,
    const float* __restrict__ n_val, float* __restrict__ out)
{
    int i = blockIdx.x * 256 + threadIdx.x;         // 65536, [d][e] flat
    int e = i & 1023, d = i >> 10;
    float nea = embed_avg[i] * DECAYF + OMDF * es[(size_t)e * DIM + d];
    out[OFF_NEA + i] = nea;
    float ncs = out[OFF_NCS + e];
    float nsum = *n_val;
    float cs = (ncs + EPSF) / (nsum + (float)N_EMBED * EPSF) * nsum;
    out[OFF_NE + i] = nea / cs;
}

extern "C" void kernel_launch(void* const* d_in, const int* in_sizes, int n_in,
                              void* d_out, int out_size, void* d_ws, size_t ws_size,
                              hipStream_t stream)
{
    const float* x            = (const float*)d_in[0];
    const float* embed        = (const float*)d_in[1];
    const float* cluster_size = (const float*)d_in[2];
    const float* embed_avg    = (const float*)d_in[3];
    float* out = (float*)d_out;
    float* ws  = (float*)d_ws;

    float* diff_sum = ws + WS_DIFF;
    float* n_val    = ws + WS_NVAL;
    float* es       = ws + WS_ES;
    float* embedT   = ws + WS_ET;
    float* cnorm    = ws + WS_CNORM;
    int*   iws      = (int*)(ws + WS_IWS);
    int*   cnt_i    = iws;
    int*   cursor_i = iws + 2 * N_EMBED;
    int*   sorted   = iws + 3 * N_EMBED;
    int*   scode    = sorted + N_TOKENS;

    vq_prep<<<261, 256, 0, stream>>>(embed, embedT, cnorm, diff_sum, cnt_i);
    vq_main<<<N_TOKENS / TOK_TILE, 256, 0, stream>>>(x, embedT, cnorm, out, diff_sum, cnt_i);
    vq_start<<<1, 1024, 0, stream>>>(cnt_i, cursor_i, cluster_size, diff_sum, out, n_val);
    vq_sort<<<N_TOKENS / 256, 256, 0, stream>>>(out, cursor_i, sorted, scode, es);
    vq_sum<<<N_TOKENS / SUM_TPB, 256, 0, stream>>>(x, sorted, scode, es);
    vq_final2<<<256, 256, 0, stream>>>(embed_avg, es, n_val, out);
}

// Round 13
// 339.453 us; speedup vs baseline: 1.0622x; 1.0622x over previous
//
#include <hip/hip_runtime.h>

#define N_TOKENS 131072
#define DIM 64
#define N_EMBED 1024
#define DECAYF 0.99f
#define OMDF 0.01f
#define EPSF 1e-5f
#define SUM_TPB 128
#define TOK_TILE 128
#define CODE_CHUNK 128
#define NCHUNK (N_EMBED / CODE_CHUNK)
#define ESTRIDE 72            // bf16 row stride (ushorts): 144 B, 16B-aligned, 4-bank shift
#define MARGIN 0.015f         // score-gap margin; score err bound ~1e-3
#define FB_BATCH 16
#define FB_BLOCKS 128

// Output layout (floats), reference return order
#define OFF_QST  ((size_t)0)
#define OFF_DIFF ((size_t)8388608)
#define OFF_IND  ((size_t)8388609)
#define OFF_NE   ((size_t)8519681)
#define OFF_NCS  ((size_t)8585217)
#define OFF_NEA  ((size_t)8586241)

// ws: floats f[0] diff_sum, f[1] n_val, f[1026..) es, f[66562..) embedT,
// f[132098..) cnorm; ints at f-idx 133632: cnt_i[1024], (pad), cursor_i@2048,
// sorted@3072, scode, nflag, flaglist
#define WS_DIFF   0
#define WS_NVAL   1
#define WS_ES     1026
#define WS_ET     66562
#define WS_CNORM  132098
#define WS_IWS    133632

typedef short bfrag8 __attribute__((ext_vector_type(8)));   // 8 bf16 (4 VGPR)
typedef float f32x4  __attribute__((ext_vector_type(4)));

__device__ inline unsigned short f2bf(float f) {
    unsigned u = __float_as_uint(f);
    u += 0x7FFFu + ((u >> 16) & 1u);                        // round-to-nearest-even
    return (unsigned short)(u >> 16);
}
__device__ inline float bf2f(unsigned short h) {
    return __uint_as_float(((unsigned)h) << 16);
}

// stage 128 rows x 64 fp32 -> hi/lo bf16 LDS (stride ESTRIDE). 256 threads.
__device__ inline void stage_bf16(const float* __restrict__ src,
                                  unsigned short* dH, unsigned short* dL, int t)
{
    const int row = t >> 1, kb = (t & 1) * 32;
    const float4* s4 = (const float4*)(src + row * 64 + kb);
#pragma unroll
    for (int jj = 0; jj < 4; ++jj) {
        float4 f0 = s4[jj * 2], f1 = s4[jj * 2 + 1];
        unsigned short h0=f2bf(f0.x),h1=f2bf(f0.y),h2=f2bf(f0.z),h3=f2bf(f0.w);
        unsigned short h4=f2bf(f1.x),h5=f2bf(f1.y),h6=f2bf(f1.z),h7=f2bf(f1.w);
        uint4 H, L;
        H.x = (unsigned)h0 | ((unsigned)h1 << 16);
        H.y = (unsigned)h2 | ((unsigned)h3 << 16);
        H.z = (unsigned)h4 | ((unsigned)h5 << 16);
        H.w = (unsigned)h6 | ((unsigned)h7 << 16);
        L.x = (unsigned)f2bf(f0.x - bf2f(h0)) | ((unsigned)f2bf(f0.y - bf2f(h1)) << 16);
        L.y = (unsigned)f2bf(f0.z - bf2f(h2)) | ((unsigned)f2bf(f0.w - bf2f(h3)) << 16);
        L.z = (unsigned)f2bf(f1.x - bf2f(h4)) | ((unsigned)f2bf(f1.y - bf2f(h5)) << 16);
        L.w = (unsigned)f2bf(f1.z - bf2f(h6)) | ((unsigned)f2bf(f1.w - bf2f(h7)) << 16);
        *(uint4*)(dH + row * ESTRIDE + kb + jj * 8) = H;
        *(uint4*)(dL + row * ESTRIDE + kb + jj * 8) = L;
    }
}

__global__ __launch_bounds__(256) void vq_prep(
    const float* __restrict__ embed, float* __restrict__ embedT,
    float* __restrict__ cnorm, float* __restrict__ diff_sum,
    int* __restrict__ cnt_i, int* __restrict__ nflag)
{
    const int b = blockIdx.x, t = threadIdx.x;
    if (b < 256) {
        int i = b * 256 + t;
        embedT[(i & 1023) * DIM + (i >> 10)] = embed[i];
    } else if (b < 260) {
        int e = (b - 256) * 256 + t;
        float s = 0.f;
#pragma unroll
        for (int d = 0; d < DIM; ++d) {
            float v = embed[d * N_EMBED + e];
            s = fmaf(v, v, s);
        }
        cnorm[e] = s;
    } else {
        for (int i = t; i < N_EMBED; i += 256) cnt_i[i] = 0;
        if (t < 2) diff_sum[t] = 0.f;
        if (t == 0) *nflag = 0;
    }
}

// bf16x3 MFMA distance GEMM + fused argmin with exact-fallback flagging.
// Block 128 tok x all 1024 codes in 8 chunks. 4 waves 2x2; wave tile 64x64;
// per wave 4x4 tiles of 16x16x32 MFMA, 3 MFMAs/tile/ktile (hh, hl, lh).
// Verified layouts: A[m=lane&15][k=q*8+j]; B[k=q*8+j][n=lane&15];
// D col=lane&15, row=q*4+reg. score = dot - 0.5*||e||^2 (maximize).
// Tokens with (best-second) < MARGIN are flagged for exact fp32 recompute.
__global__ __launch_bounds__(256, 1) void vq_main(
    const float* __restrict__ x, const float* __restrict__ embedT,
    const float* __restrict__ cnorm, float* __restrict__ out,
    float* __restrict__ diff_sum, int* __restrict__ cnt_i,
    int* __restrict__ nflag, int* __restrict__ flaglist)
{
    __shared__ __align__(16) unsigned short sm[4 * 128 * ESTRIDE];  // 73728 B
    unsigned short* xh = sm;
    unsigned short* xl = sm + 128 * ESTRIDE;
    unsigned short* eh = sm + 2 * 128 * ESTRIDE;
    unsigned short* el = sm + 3 * 128 * ESTRIDE;
    // post-loop aliases (frag buffers dead after chunk loop)
    int*   lhist = (int*)sm;                          // 4096 B over xh
    float* red_b = (float*)(sm + 128 * ESTRIDE);      // over xl
    float* red_s = red_b + 256;
    int*   red_i = (int*)(red_s + 256);
    int*   bi_l  = red_i + 256;                       // 128 ints

    const int t = threadIdx.x;
    const int w = t >> 6, lane = t & 63;
    const int wr = w >> 1, wc = w & 1;
    const int col = lane & 15, q = lane >> 4;

    stage_bf16(x + (size_t)blockIdx.x * TOK_TILE * DIM, xh, xl, t);

    float best[16], sec[16];
    int   bidx[16];
#pragma unroll
    for (int s = 0; s < 16; ++s) { best[s] = -3.4e38f; sec[s] = -3.4e38f; bidx[s] = 0; }

    const int abase = (wr * 64 + col) * ESTRIDE + q * 8;
    const int bbase = (wc * 64 + col) * ESTRIDE + q * 8;

    for (int chunk = 0; chunk < NCHUNK; ++chunk) {
        __syncthreads();                               // prev chunk frag reads done
        stage_bf16(embedT + (size_t)chunk * CODE_CHUNK * DIM, eh, el, t);
        __syncthreads();

        f32x4 acc[4][4];
#pragma unroll
        for (int i = 0; i < 4; ++i)
#pragma unroll
            for (int j = 0; j < 4; ++j) acc[i][j] = (f32x4){0.f, 0.f, 0.f, 0.f};

#pragma unroll 1
        for (int kt = 0; kt < 2; ++kt) {
            bfrag8 ah[4], al[4];
#pragma unroll
            for (int i = 0; i < 4; ++i) {
                ah[i] = *(const bfrag8*)(xh + abase + i * 16 * ESTRIDE + kt * 32);
                al[i] = *(const bfrag8*)(xl + abase + i * 16 * ESTRIDE + kt * 32);
            }
#pragma unroll
            for (int j = 0; j < 4; ++j) {
                bfrag8 bh = *(const bfrag8*)(eh + bbase + j * 16 * ESTRIDE + kt * 32);
                bfrag8 bl = *(const bfrag8*)(el + bbase + j * 16 * ESTRIDE + kt * 32);
#pragma unroll
                for (int i = 0; i < 4; ++i) {
                    acc[i][j] = __builtin_amdgcn_mfma_f32_16x16x32_bf16(ah[i], bh, acc[i][j], 0, 0, 0);
                    acc[i][j] = __builtin_amdgcn_mfma_f32_16x16x32_bf16(ah[i], bl, acc[i][j], 0, 0, 0);
                    acc[i][j] = __builtin_amdgcn_mfma_f32_16x16x32_bf16(al[i], bh, acc[i][j], 0, 0, 0);
                }
            }
        }

        // running best/second (scores; no tie logic needed — ties get flagged)
#pragma unroll
        for (int j = 0; j < 4; ++j) {
            int code = chunk * CODE_CHUNK + wc * 64 + j * 16 + col;
            float cnj = 0.5f * cnorm[code];
#pragma unroll
            for (int i = 0; i < 4; ++i) {
#pragma unroll
                for (int r = 0; r < 4; ++r) {
                    float sc = acc[i][j][r] - cnj;
                    int s = i * 4 + r;
                    sec[s] = fmaxf(sec[s], fminf(best[s], sc));
                    bidx[s] = (sc > best[s]) ? code : bidx[s];
                    best[s] = fmaxf(best[s], sc);
                }
            }
        }
    }

    // re-init lhist (aliases xh; frag buffers now dead)
    for (int i = t; i < N_EMBED; i += 256) lhist[i] = 0;

    // intra-quad butterfly over the 16 code-columns
#pragma unroll
    for (int s = 0; s < 16; ++s) {
#pragma unroll
        for (int m = 1; m < 16; m <<= 1) {
            float b2 = __shfl_xor(best[s], m, 64);
            float s2 = __shfl_xor(sec[s],  m, 64);
            int   i2 = __shfl_xor(bidx[s], m, 64);
            float mn = fminf(best[s], b2);
            sec[s]  = fmaxf(fmaxf(sec[s], s2), mn);
            bidx[s] = (b2 > best[s]) ? i2 : bidx[s];
            best[s] = fmaxf(best[s], b2);
        }
    }
    if (col == 0) {
#pragma unroll
        for (int i = 0; i < 4; ++i)
#pragma unroll
            for (int r = 0; r < 4; ++r) {
                int tl = wr * 64 + i * 16 + q * 4 + r;
                red_b[wc * 128 + tl] = best[i * 4 + r];
                red_s[wc * 128 + tl] = sec[i * 4 + r];
                red_i[wc * 128 + tl] = bidx[i * 4 + r];
            }
    }
    __syncthreads();

    if (t < TOK_TILE) {
        float b0 = red_b[t], b1 = red_b[128 + t];
        float s0 = red_s[t], s1 = red_s[128 + t];
        int   i0 = red_i[t], i1 = red_i[128 + t];
        float B = fmaxf(b0, b1);
        float S = fmaxf(fmaxf(s0, s1), fminf(b0, b1));
        int idx = (b1 > b0) ? i1 : i0;
        bool flag = (B - S) < MARGIN;
        bi_l[t] = idx | (flag ? 0x10000 : 0);
        int token = blockIdx.x * TOK_TILE + t;
        out[OFF_IND + token] = (float)idx;             // fallback overwrites flagged
        if (flag) { int p = atomicAdd(nflag, 1); flaglist[p] = token; }
        else atomicAdd(&lhist[idx], 1);
    }
    __syncthreads();

    // quantize + diff for unflagged tokens (x reloaded from global, coalesced)
    float ds = 0.f;
    {
        const float4* et4 = (const float4*)embedT;
        const float4* xs4 = (const float4*)(x + (size_t)blockIdx.x * TOK_TILE * DIM);
        float4* qst = (float4*)(out + OFF_QST + (size_t)blockIdx.x * TOK_TILE * DIM);
#pragma unroll
        for (int j = 0; j < 8; ++j) {
            int g = j * 256 + t;
            int tok = g >> 4, f = g & 15;
            int bir = bi_l[tok];
            int bi = bir & 0xFFFF;
            float4 qv = et4[bi * 16 + f];
            float4 xv = xs4[g];
            if (!(bir & 0x10000)) {
                qst[g] = qv;
                float ex = qv.x - xv.x, ey = qv.y - xv.y;
                float ez = qv.z - xv.z, ew = qv.w - xv.w;
                ds = fmaf(ex, ex, ds); ds = fmaf(ey, ey, ds);
                ds = fmaf(ez, ez, ds); ds = fmaf(ew, ew, ds);
            }
        }
    }
#pragma unroll
    for (int o = 32; o > 0; o >>= 1) ds += __shfl_down(ds, o, 64);
    if (lane == 0) atomicAdd(diff_sum, ds);

    for (int i = t; i < N_EMBED; i += 256) {
        int cv = lhist[i];
        if (cv) atomicAdd(&cnt_i[i], cv);
    }
}

// Exact fp32 recompute for flagged tokens (batched, LDS-staged codebook).
__global__ __launch_bounds__(256) void vq_fallback(
    const float* __restrict__ x, const float* __restrict__ embedT,
    const float* __restrict__ cnorm, float* __restrict__ out,
    float* __restrict__ diff_sum, int* __restrict__ cnt_i,
    const int* __restrict__ nflag, const int* __restrict__ flaglist)
{
    __shared__ float xr[FB_BATCH][68];      // +4 pad: tok-groups spread banks
    __shared__ float ec[128][68];           // 34816 B code chunk, aligned f4 rows
    __shared__ float rd[FB_BATCH][16];
    __shared__ int   ri[FB_BATCH][16];
    __shared__ int   win[FB_BATCH];
    __shared__ int   toks[FB_BATCH];

    const int t = threadIdx.x;
    const int nf = *nflag;

    for (int base = blockIdx.x * FB_BATCH; base < nf; base += gridDim.x * FB_BATCH) {
        __syncthreads();                               // prev iteration done
        if (t < FB_BATCH) toks[t] = (base + t < nf) ? flaglist[base + t] : -1;
        __syncthreads();
        for (int i = t; i < FB_BATCH * 64; i += 256) {
            int tk = i >> 6, d = i & 63;
            int token = toks[tk];
            xr[tk][d] = (token >= 0) ? x[(size_t)token * DIM + d] : 0.f;
        }
        float bd = 3.4e38f; int be = 0;
        const int tok = t >> 4, l16 = t & 15;
        for (int ch = 0; ch < 8; ++ch) {
            __syncthreads();
            {
                const float4* src = (const float4*)(embedT + (size_t)ch * 128 * DIM);
                for (int i = t; i < 2048; i += 256) {
                    int row = i >> 4, kp = (i & 15) << 2;
                    *(float4*)(&ec[row][kp]) = src[i];
                }
            }
            __syncthreads();
#pragma unroll 1
            for (int cc = 0; cc < 8; ++cc) {
                int lc = l16 + cc * 16;                // thread-strided rows
                float d0 = 0.f, d1 = 0.f, d2 = 0.f, d3 = 0.f;
#pragma unroll
                for (int k4 = 0; k4 < 16; ++k4) {
                    float4 a = *(const float4*)(&xr[tok][k4 << 2]);
                    float4 b = *(const float4*)(&ec[lc][k4 << 2]);
                    d0 = fmaf(a.x, b.x, d0); d1 = fmaf(a.y, b.y, d1);
                    d2 = fmaf(a.z, b.z, d2); d3 = fmaf(a.w, b.w, d3);
                }
                int ge = ch * 128 + lc;
                float dist = fmaf(-2.f, (d0 + d1) + (d2 + d3), cnorm[ge]);
                if (dist < bd) { bd = dist; be = ge; } // ascending ge per thread
            }
        }
        rd[tok][l16] = bd; ri[tok][l16] = be;
        __syncthreads();
        if (t < FB_BATCH) {
            float d0 = rd[t][0]; int e0 = ri[t][0];
#pragma unroll
            for (int i = 1; i < 16; ++i) {
                float di = rd[t][i]; int ei = ri[t][i];
                if (di < d0 || (di == d0 && ei < e0)) { d0 = di; e0 = ei; }
            }
            win[t] = e0;
            int token = toks[t];
            if (token >= 0) {
                out[OFF_IND + token] = (float)e0;
                atomicAdd(&cnt_i[e0], 1);
            }
        }
        __syncthreads();
        float ds = 0.f;
        for (int i = t; i < FB_BATCH * 64; i += 256) {
            int tk = i >> 6, d = i & 63;
            int token = toks[tk];
            if (token >= 0) {
                float qv = embedT[(size_t)win[tk] * DIM + d];
                out[OFF_QST + (size_t)token * DIM + d] = qv;
                float e = qv - xr[tk][d];
                ds = fmaf(e, e, ds);
            }
        }
#pragma unroll
        for (int o = 32; o > 0; o >>= 1) ds += __shfl_down(ds, o, 64);
        if ((t & 63) == 0 && ds != 0.f) atomicAdd(diff_sum, ds);
    }
}

// single block 1024: prefix scan + EMA cluster size + n + diff finalize
__global__ __launch_bounds__(1024) void vq_start(
    const int* __restrict__ cnt_i, int* __restrict__ cursor_i,
    const float* __restrict__ cluster_size, const float* __restrict__ diff_sum,
    float* __restrict__ out, float* __restrict__ n_val)
{
    __shared__ int sc[N_EMBED];
    __shared__ float red[16];
    int e = threadIdx.x;
    int c = cnt_i[e];
    sc[e] = c;

    float ncs = cluster_size[e] * DECAYF + OMDF * (float)c;
    out[OFF_NCS + e] = ncs;
    float s = ncs;
#pragma unroll
    for (int o = 32; o > 0; o >>= 1) s += __shfl_down(s, o, 64);
    if ((e & 63) == 0) red[e >> 6] = s;
    __syncthreads();

#pragma unroll
    for (int off = 1; off < N_EMBED; off <<= 1) {
        int v = (e >= off) ? sc[e - off] : 0;
        __syncthreads();
        sc[e] += v;
        __syncthreads();
    }
    cursor_i[e] = sc[e] - c;

    if (e == 0) {
        float nsum = 0.f;
#pragma unroll
        for (int i = 0; i < 16; ++i) nsum += red[i];
        *n_val = nsum;
        out[OFF_DIFF] = *diff_sum / (float)((size_t)N_TOKENS * DIM);
    }
}

__global__ __launch_bounds__(256) void vq_sort(
    const float* __restrict__ out, int* __restrict__ cursor_i,
    int* __restrict__ sorted, int* __restrict__ scode,
    float* __restrict__ es)
{
    __shared__ int lh[N_EMBED];
    __shared__ int lbase[N_EMBED];
    int t = threadIdx.x;
    if (blockIdx.x < 256) es[blockIdx.x * 256 + t] = 0.f;
    for (int i = t; i < N_EMBED; i += 256) lh[i] = 0;
    __syncthreads();
    int tok = blockIdx.x * 256 + t;
    int e = (int)out[OFF_IND + tok];
    int p = atomicAdd(&lh[e], 1);
    __syncthreads();
    for (int i = t; i < N_EMBED; i += 256) {
        int c = lh[i];
        if (c) lbase[i] = atomicAdd(&cursor_i[i], c);
    }
    __syncthreads();
    int pos = lbase[e] + p;
    sorted[pos] = tok;
    scode[pos] = e;
}

__global__ __launch_bounds__(256) void vq_sum(
    const float* __restrict__ x, const int* __restrict__ sorted,
    const int* __restrict__ scode, float* __restrict__ es)
{
    __shared__ int ltok[SUM_TPB];
    __shared__ int lcode[SUM_TPB];
    const int t = threadIdx.x;
    const int base = blockIdx.x * SUM_TPB;
    if (t < SUM_TPB) {
        ltok[t]  = sorted[base + t];
        lcode[t] = scode[base + t];
    }
    __syncthreads();

    const int w = t >> 6, d = t & 63;
    const int i0 = w * (SUM_TPB / 4);
    int   cur = lcode[i0];
    float acc = 0.f;
#pragma unroll 4
    for (int i = i0; i < i0 + SUM_TPB / 4; ++i) {
        int e = lcode[i];
        if (e != cur) {
            atomicAdd(&es[(size_t)cur * DIM + d], acc);
            acc = 0.f;
            cur = e;
        }
        acc += x[(size_t)ltok[i] * DIM + d];
    }
    atomicAdd(&es[(size_t)cur * DIM + d], acc);
}

__global__ __launch_bounds__(256) void vq_final2(
    const float* __restrict__ embed_avg, const float* __restrict__ es,
    const float* __restrict__ n_val, float* __restrict__ out)
{
    int i = blockIdx.x * 256 + threadIdx.x;
    int e = i & 1023, d = i >> 10;
    float nea = embed_avg[i] * DECAYF + OMDF * es[(size_t)e * DIM + d];
    out[OFF_NEA + i] = nea;
    float ncs = out[OFF_NCS + e];
    float nsum = *n_val;
    float cs = (ncs + EPSF) / (nsum + (float)N_EMBED * EPSF) * nsum;
    out[OFF_NE + i] = nea / cs;
}

extern "C" void kernel_launch(void* const* d_in, const int* in_sizes, int n_in,
                              void* d_out, int out_size, void* d_ws, size_t ws_size,
                              hipStream_t stream)
{
    const float* x            = (const float*)d_in[0];
    const float* embed        = (const float*)d_in[1];
    const float* cluster_size = (const float*)d_in[2];
    const float* embed_avg    = (const float*)d_in[3];
    float* out = (float*)d_out;
    float* ws  = (float*)d_ws;

    float* diff_sum = ws + WS_DIFF;
    float* n_val    = ws + WS_NVAL;
    float* es       = ws + WS_ES;
    float* embedT   = ws + WS_ET;
    float* cnorm    = ws + WS_CNORM;
    int*   iws      = (int*)(ws + WS_IWS);
    int*   cnt_i    = iws;
    int*   cursor_i = iws + 2 * N_EMBED;
    int*   sorted   = iws + 3 * N_EMBED;
    int*   scode    = sorted + N_TOKENS;
    int*   nflag    = scode + N_TOKENS;
    int*   flaglist = nflag + 1;

    vq_prep<<<261, 256, 0, stream>>>(embed, embedT, cnorm, diff_sum, cnt_i, nflag);
    vq_main<<<N_TOKENS / TOK_TILE, 256, 0, stream>>>(x, embedT, cnorm, out,
                                                     diff_sum, cnt_i, nflag, flaglist);
    vq_fallback<<<FB_BLOCKS, 256, 0, stream>>>(x, embedT, cnorm, out,
                                               diff_sum, cnt_i, nflag, flaglist);
    vq_start<<<1, 1024, 0, stream>>>(cnt_i, cursor_i, cluster_size, diff_sum, out, n_val);
    vq_sort<<<N_TOKENS / 256, 256, 0, stream>>>(out, cursor_i, sorted, scode, es);
    vq_sum<<<N_TOKENS / SUM_TPB, 256, 0, stream>>>(x, sorted, scode, es);
    vq_final2<<<256, 256, 0, stream>>>(embed_avg, es, n_val, out);
}

// Round 14
// 338.228 us; speedup vs baseline: 1.0660x; 1.0036x over previous
//
#include <hip/hip_runtime.h>

#define N_TOKENS 131072
#define DIM 64
#define N_EMBED 1024
#define DECAYF 0.99f
#define OMDF 0.01f
#define EPSF 1e-5f
#define SUM_TPB 128
#define TOK_TILE 128
#define CODE_CHUNK 128
#define NCHUNK (N_EMBED / CODE_CHUNK)
#define MARGIN 0.004f         // 8x the ~5e-4 bf16x3 score error bound
#define FB_BATCH 16
#define FB_BLOCKS 128

// Output layout (floats), reference return order
#define OFF_QST  ((size_t)0)
#define OFF_DIFF ((size_t)8388608)
#define OFF_IND  ((size_t)8388609)
#define OFF_NE   ((size_t)8519681)
#define OFF_NCS  ((size_t)8585217)
#define OFF_NEA  ((size_t)8586241)

// ws: floats f[0] diff_sum, f[1] n_val, f[1026..) es, f[66562..) embedT,
// f[132098..) cnorm; ints at f-idx 133632: cnt_i@0, cursor_i@2048,
// sorted@3072, scode, nflag, flaglist(16-pad), then bf16 codebook eh_g/el_g.
#define WS_DIFF   0
#define WS_NVAL   1
#define WS_ES     1026
#define WS_ET     66562
#define WS_CNORM  132098
#define WS_IWS    133632

typedef short bfrag8 __attribute__((ext_vector_type(8)));   // 8 bf16 (4 VGPR)
typedef float f32x4  __attribute__((ext_vector_type(4)));

__device__ inline unsigned short f2bf(float f) {
    unsigned u = __float_as_uint(f);
    u += 0x7FFFu + ((u >> 16) & 1u);                        // round-to-nearest-even
    return (unsigned short)(u >> 16);
}
__device__ inline float bf2f(unsigned short h) {
    return __uint_as_float(((unsigned)h) << 16);
}
// 8 fp32 -> packed hi/lo bf16 fragments (in registers)
__device__ inline void cvt8(float4 f0, float4 f1, bfrag8* hi, bfrag8* lo) {
    union { bfrag8 v; unsigned u[4]; } H, L;
    unsigned short h0=f2bf(f0.x), h1=f2bf(f0.y), h2=f2bf(f0.z), h3=f2bf(f0.w);
    unsigned short h4=f2bf(f1.x), h5=f2bf(f1.y), h6=f2bf(f1.z), h7=f2bf(f1.w);
    H.u[0]=(unsigned)h0|((unsigned)h1<<16); H.u[1]=(unsigned)h2|((unsigned)h3<<16);
    H.u[2]=(unsigned)h4|((unsigned)h5<<16); H.u[3]=(unsigned)h6|((unsigned)h7<<16);
    L.u[0]=(unsigned)f2bf(f0.x-bf2f(h0))|((unsigned)f2bf(f0.y-bf2f(h1))<<16);
    L.u[1]=(unsigned)f2bf(f0.z-bf2f(h2))|((unsigned)f2bf(f0.w-bf2f(h3))<<16);
    L.u[2]=(unsigned)f2bf(f1.x-bf2f(h4))|((unsigned)f2bf(f1.y-bf2f(h5))<<16);
    L.u[3]=(unsigned)f2bf(f1.z-bf2f(h6))|((unsigned)f2bf(f1.w-bf2f(h7))<<16);
    *hi = H.v; *lo = L.v;
}

// Prep: transpose embed -> embedT (fp32) AND pre-convert codebook to packed
// bf16 hi/lo (eh_g/el_g) ONCE (r13 re-converted it in every vq_main block).
__global__ __launch_bounds__(256) void vq_prep(
    const float* __restrict__ embed, float* __restrict__ embedT,
    float* __restrict__ cnorm, float* __restrict__ diff_sum,
    int* __restrict__ cnt_i, int* __restrict__ nflag,
    unsigned short* __restrict__ eh_g, unsigned short* __restrict__ el_g)
{
    const int b = blockIdx.x, t = threadIdx.x;
    if (b < 256) {
        int i = b * 256 + t;
        int d = i >> 10, e = i & 1023;
        float v = embed[i];
        embedT[e * DIM + d] = v;
        unsigned short h = f2bf(v);
        eh_g[e * DIM + d] = h;
        el_g[e * DIM + d] = f2bf(v - bf2f(h));
    } else if (b < 260) {
        int e = (b - 256) * 256 + t;
        float s = 0.f;
#pragma unroll
        for (int d = 0; d < DIM; ++d) {
            float v = embed[d * N_EMBED + e];
            s = fmaf(v, v, s);
        }
        cnorm[e] = s;
    } else {
        for (int i = t; i < N_EMBED; i += 256) cnt_i[i] = 0;
        if (t < 2) diff_sum[t] = 0.f;
        if (t == 0) *nflag = 0;
    }
}

// bf16x3 MFMA distance GEMM, NO LDS in the main loop:
// A-frags (x tile) built once in 16 named registers; B-frags streamed from
// pre-converted global bf16 with a one-slot prefetch (2 loads : 12 MFMAs).
// Layouts (r13-verified): A[m=lane&15][k=q*8+j]; B[k][n=lane&15];
// D col=lane&15,row=q*4+reg. score = dot - 0.5||e||^2 (maximize).
// Tokens with (best-second) < MARGIN flagged for exact fp32 recompute.
__global__ __launch_bounds__(256, 1) void vq_main(
    const float* __restrict__ x, const float* __restrict__ embedT,
    const unsigned short* __restrict__ eh_g, const unsigned short* __restrict__ el_g,
    const float* __restrict__ cnorm, float* __restrict__ out,
    float* __restrict__ diff_sum, int* __restrict__ cnt_i,
    int* __restrict__ nflag, int* __restrict__ flaglist)
{
    __shared__ float red_b[256];
    __shared__ float red_s[256];
    __shared__ int   red_i[256];
    __shared__ int   bi_l[TOK_TILE];
    __shared__ int   lhist[N_EMBED];            // ~7.7 KB total

    const int t = threadIdx.x;
    const int w = t >> 6, lane = t & 63;
    const int wr = w >> 1, wc = w & 1;
    const int col = lane & 15, q = lane >> 4;
    const int qk = q * 8;

    for (int i = t; i < N_EMBED; i += 256) lhist[i] = 0;

    // A-frags: 16 named bfrag8 (r10 lesson: arrays spanning runtime loops
    // get alloca'd; named scalars stay in VGPRs).
    bfrag8 ah0_0, ah0_1, ah0_2, ah0_3, ah1_0, ah1_1, ah1_2, ah1_3;
    bfrag8 al0_0, al0_1, al0_2, al0_3, al1_0, al1_1, al1_2, al1_3;
    {
        const float* xrb = x + ((size_t)blockIdx.x * TOK_TILE + wr * 64 + col) * DIM;
#define MAKE_A(KT, I, AH, AL) { \
        const float* p_ = xrb + (I) * 16 * DIM + (KT) * 32 + qk; \
        cvt8(*(const float4*)p_, *(const float4*)(p_ + 4), &AH, &AL); }
        MAKE_A(0,0,ah0_0,al0_0) MAKE_A(0,1,ah0_1,al0_1)
        MAKE_A(0,2,ah0_2,al0_2) MAKE_A(0,3,ah0_3,al0_3)
        MAKE_A(1,0,ah1_0,al1_0) MAKE_A(1,1,ah1_1,al1_1)
        MAKE_A(1,2,ah1_2,al1_2) MAKE_A(1,3,ah1_3,al1_3)
#undef MAKE_A
    }

    float best[16], sec[16];
    int   bidx[16];
#pragma unroll
    for (int s = 0; s < 16; ++s) { best[s] = -3.4e38f; sec[s] = -3.4e38f; bidx[s] = 0; }

    // slot g = chunk*8 + s; s: kt = s>>2, j = s&3
    bfrag8 nbh, nbl;
    {
        int cb = ((wc * 64 + col) << 6) + qk;          // g = 0
        nbh = *(const bfrag8*)(eh_g + cb);
        nbl = *(const bfrag8*)(el_g + cb);
    }

#define MM3(AH,AL,BH,BL,J) \
    acc[0][J]=__builtin_amdgcn_mfma_f32_16x16x32_bf16(AH##_0,BH,acc[0][J],0,0,0); \
    acc[1][J]=__builtin_amdgcn_mfma_f32_16x16x32_bf16(AH##_1,BH,acc[1][J],0,0,0); \
    acc[2][J]=__builtin_amdgcn_mfma_f32_16x16x32_bf16(AH##_2,BH,acc[2][J],0,0,0); \
    acc[3][J]=__builtin_amdgcn_mfma_f32_16x16x32_bf16(AH##_3,BH,acc[3][J],0,0,0); \
    acc[0][J]=__builtin_amdgcn_mfma_f32_16x16x32_bf16(AH##_0,BL,acc[0][J],0,0,0); \
    acc[1][J]=__builtin_amdgcn_mfma_f32_16x16x32_bf16(AH##_1,BL,acc[1][J],0,0,0); \
    acc[2][J]=__builtin_amdgcn_mfma_f32_16x16x32_bf16(AH##_2,BL,acc[2][J],0,0,0); \
    acc[3][J]=__builtin_amdgcn_mfma_f32_16x16x32_bf16(AH##_3,BL,acc[3][J],0,0,0); \
    acc[0][J]=__builtin_amdgcn_mfma_f32_16x16x32_bf16(AL##_0,BH,acc[0][J],0,0,0); \
    acc[1][J]=__builtin_amdgcn_mfma_f32_16x16x32_bf16(AL##_1,BH,acc[1][J],0,0,0); \
    acc[2][J]=__builtin_amdgcn_mfma_f32_16x16x32_bf16(AL##_2,BH,acc[2][J],0,0,0); \
    acc[3][J]=__builtin_amdgcn_mfma_f32_16x16x32_bf16(AL##_3,BH,acc[3][J],0,0,0);

#define SLOT(KT, S) { \
    bfrag8 bh_ = nbh, bl_ = nbl; \
    int gn_ = g0 + (S) + 1; gn_ = (gn_ > 63) ? 63 : gn_; \
    int cb_ = (((gn_ >> 3) * 128 + wc * 64 + (gn_ & 3) * 16 + col) << 6) \
              + ((gn_ >> 2) & 1) * 32 + qk; \
    nbh = *(const bfrag8*)(eh_g + cb_); \
    nbl = *(const bfrag8*)(el_g + cb_); \
    MM3(ah##KT, al##KT, bh_, bl_, ((S) & 3)) }

#pragma unroll 1
    for (int chunk = 0; chunk < NCHUNK; ++chunk) {
        const int g0 = chunk * 8;
        f32x4 acc[4][4];
#pragma unroll
        for (int i = 0; i < 4; ++i)
#pragma unroll
            for (int j = 0; j < 4; ++j) acc[i][j] = (f32x4){0.f, 0.f, 0.f, 0.f};

        SLOT(0,0) SLOT(0,1) SLOT(0,2) SLOT(0,3)
        SLOT(1,4) SLOT(1,5) SLOT(1,6) SLOT(1,7)

        // running best/second (ties land inside MARGIN -> flagged -> exact)
#pragma unroll
        for (int j = 0; j < 4; ++j) {
            int code = chunk * CODE_CHUNK + wc * 64 + j * 16 + col;
            float cnj = 0.5f * cnorm[code];
#pragma unroll
            for (int i = 0; i < 4; ++i) {
#pragma unroll
                for (int r = 0; r < 4; ++r) {
                    float sc = acc[i][j][r] - cnj;
                    int s = i * 4 + r;
                    sec[s] = fmaxf(sec[s], fminf(best[s], sc));
                    bidx[s] = (sc > best[s]) ? code : bidx[s];
                    best[s] = fmaxf(best[s], sc);
                }
            }
        }
    }
#undef SLOT
#undef MM3

    // intra-quad butterfly over the 16 code-columns
#pragma unroll
    for (int s = 0; s < 16; ++s) {
#pragma unroll
        for (int m = 1; m < 16; m <<= 1) {
            float b2 = __shfl_xor(best[s], m, 64);
            float s2 = __shfl_xor(sec[s],  m, 64);
            int   i2 = __shfl_xor(bidx[s], m, 64);
            float mn = fminf(best[s], b2);
            sec[s]  = fmaxf(fmaxf(sec[s], s2), mn);
            bidx[s] = (b2 > best[s]) ? i2 : bidx[s];
            best[s] = fmaxf(best[s], b2);
        }
    }
    if (col == 0) {
#pragma unroll
        for (int i = 0; i < 4; ++i)
#pragma unroll
            for (int r = 0; r < 4; ++r) {
                int tl = wr * 64 + i * 16 + q * 4 + r;
                red_b[wc * 128 + tl] = best[i * 4 + r];
                red_s[wc * 128 + tl] = sec[i * 4 + r];
                red_i[wc * 128 + tl] = bidx[i * 4 + r];
            }
    }
    __syncthreads();

    if (t < TOK_TILE) {
        float b0 = red_b[t], b1 = red_b[128 + t];
        float s0 = red_s[t], s1 = red_s[128 + t];
        int   i0 = red_i[t], i1 = red_i[128 + t];
        float B = fmaxf(b0, b1);
        float S = fmaxf(fmaxf(s0, s1), fminf(b0, b1));
        int idx = (b1 > b0) ? i1 : i0;
        bool flag = (B - S) < MARGIN;
        bi_l[t] = idx | (flag ? 0x10000 : 0);
        int token = blockIdx.x * TOK_TILE + t;
        out[OFF_IND + token] = (float)idx;             // fallback overwrites flagged
        if (flag) { int p = atomicAdd(nflag, 1); flaglist[p] = token; }
        else atomicAdd(&lhist[idx], 1);
    }
    __syncthreads();

    // quantize + diff for unflagged tokens
    float ds = 0.f;
    {
        const float4* et4 = (const float4*)embedT;
        const float4* xs4 = (const float4*)(x + (size_t)blockIdx.x * TOK_TILE * DIM);
        float4* qst = (float4*)(out + OFF_QST + (size_t)blockIdx.x * TOK_TILE * DIM);
#pragma unroll
        for (int j = 0; j < 8; ++j) {
            int g = j * 256 + t;
            int tok = g >> 4, f = g & 15;
            int bir = bi_l[tok];
            int bi = bir & 0xFFFF;
            float4 qv = et4[bi * 16 + f];
            float4 xv = xs4[g];
            if (!(bir & 0x10000)) {
                qst[g] = qv;
                float ex = qv.x - xv.x, ey = qv.y - xv.y;
                float ez = qv.z - xv.z, ew = qv.w - xv.w;
                ds = fmaf(ex, ex, ds); ds = fmaf(ey, ey, ds);
                ds = fmaf(ez, ez, ds); ds = fmaf(ew, ew, ds);
            }
        }
    }
#pragma unroll
    for (int o = 32; o > 0; o >>= 1) ds += __shfl_down(ds, o, 64);
    if (lane == 0) atomicAdd(diff_sum, ds);

    for (int i = t; i < N_EMBED; i += 256) {
        int cv = lhist[i];
        if (cv) atomicAdd(&cnt_i[i], cv);
    }
}

// Exact fp32 recompute for flagged tokens (batched, LDS-staged codebook).
__global__ __launch_bounds__(256) void vq_fallback(
    const float* __restrict__ x, const float* __restrict__ embedT,
    const float* __restrict__ cnorm, float* __restrict__ out,
    float* __restrict__ diff_sum, int* __restrict__ cnt_i,
    const int* __restrict__ nflag, const int* __restrict__ flaglist)
{
    __shared__ float xr[FB_BATCH][68];
    __shared__ float ec[128][68];
    __shared__ float rd[FB_BATCH][16];
    __shared__ int   ri[FB_BATCH][16];
    __shared__ int   win[FB_BATCH];
    __shared__ int   toks[FB_BATCH];

    const int t = threadIdx.x;
    const int nf = *nflag;

    for (int base = blockIdx.x * FB_BATCH; base < nf; base += gridDim.x * FB_BATCH) {
        __syncthreads();
        if (t < FB_BATCH) toks[t] = (base + t < nf) ? flaglist[base + t] : -1;
        __syncthreads();
        for (int i = t; i < FB_BATCH * 64; i += 256) {
            int tk = i >> 6, d = i & 63;
            int token = toks[tk];
            xr[tk][d] = (token >= 0) ? x[(size_t)token * DIM + d] : 0.f;
        }
        float bd = 3.4e38f; int be = 0;
        const int tok = t >> 4, l16 = t & 15;
        for (int ch = 0; ch < 8; ++ch) {
            __syncthreads();
            {
                const float4* src = (const float4*)(embedT + (size_t)ch * 128 * DIM);
                for (int i = t; i < 2048; i += 256) {
                    int row = i >> 4, kp = (i & 15) << 2;
                    *(float4*)(&ec[row][kp]) = src[i];
                }
            }
            __syncthreads();
#pragma unroll 1
            for (int cc = 0; cc < 8; ++cc) {
                int lc = l16 + cc * 16;
                float d0 = 0.f, d1 = 0.f, d2 = 0.f, d3 = 0.f;
#pragma unroll
                for (int k4 = 0; k4 < 16; ++k4) {
                    float4 a = *(const float4*)(&xr[tok][k4 << 2]);
                    float4 b = *(const float4*)(&ec[lc][k4 << 2]);
                    d0 = fmaf(a.x, b.x, d0); d1 = fmaf(a.y, b.y, d1);
                    d2 = fmaf(a.z, b.z, d2); d3 = fmaf(a.w, b.w, d3);
                }
                int ge = ch * 128 + lc;
                float dist = fmaf(-2.f, (d0 + d1) + (d2 + d3), cnorm[ge]);
                if (dist < bd) { bd = dist; be = ge; }
            }
        }
        rd[tok][l16] = bd; ri[tok][l16] = be;
        __syncthreads();
        if (t < FB_BATCH) {
            float d0 = rd[t][0]; int e0 = ri[t][0];
#pragma unroll
            for (int i = 1; i < 16; ++i) {
                float di = rd[t][i]; int ei = ri[t][i];
                if (di < d0 || (di == d0 && ei < e0)) { d0 = di; e0 = ei; }
            }
            win[t] = e0;
            int token = toks[t];
            if (token >= 0) {
                out[OFF_IND + token] = (float)e0;
                atomicAdd(&cnt_i[e0], 1);
            }
        }
        __syncthreads();
        float ds = 0.f;
        for (int i = t; i < FB_BATCH * 64; i += 256) {
            int tk = i >> 6, d = i & 63;
            int token = toks[tk];
            if (token >= 0) {
                float qv = embedT[(size_t)win[tk] * DIM + d];
                out[OFF_QST + (size_t)token * DIM + d] = qv;
                float e = qv - xr[tk][d];
                ds = fmaf(e, e, ds);
            }
        }
#pragma unroll
        for (int o = 32; o > 0; o >>= 1) ds += __shfl_down(ds, o, 64);
        if ((t & 63) == 0 && ds != 0.f) atomicAdd(diff_sum, ds);
    }
}

// single block 1024: prefix scan + EMA cluster size + n + diff finalize
__global__ __launch_bounds__(1024) void vq_start(
    const int* __restrict__ cnt_i, int* __restrict__ cursor_i,
    const float* __restrict__ cluster_size, const float* __restrict__ diff_sum,
    float* __restrict__ out, float* __restrict__ n_val)
{
    __shared__ int sc[N_EMBED];
    __shared__ float red[16];
    int e = threadIdx.x;
    int c = cnt_i[e];
    sc[e] = c;

    float ncs = cluster_size[e] * DECAYF + OMDF * (float)c;
    out[OFF_NCS + e] = ncs;
    float s = ncs;
#pragma unroll
    for (int o = 32; o > 0; o >>= 1) s += __shfl_down(s, o, 64);
    if ((e & 63) == 0) red[e >> 6] = s;
    __syncthreads();

#pragma unroll
    for (int off = 1; off < N_EMBED; off <<= 1) {
        int v = (e >= off) ? sc[e - off] : 0;
        __syncthreads();
        sc[e] += v;
        __syncthreads();
    }
    cursor_i[e] = sc[e] - c;

    if (e == 0) {
        float nsum = 0.f;
#pragma unroll
        for (int i = 0; i < 16; ++i) nsum += red[i];
        *n_val = nsum;
        out[OFF_DIFF] = *diff_sum / (float)((size_t)N_TOKENS * DIM);
    }
}

__global__ __launch_bounds__(256) void vq_sort(
    const float* __restrict__ out, int* __restrict__ cursor_i,
    int* __restrict__ sorted, int* __restrict__ scode,
    float* __restrict__ es)
{
    __shared__ int lh[N_EMBED];
    __shared__ int lbase[N_EMBED];
    int t = threadIdx.x;
    if (blockIdx.x < 256) es[blockIdx.x * 256 + t] = 0.f;
    for (int i = t; i < N_EMBED; i += 256) lh[i] = 0;
    __syncthreads();
    int tok = blockIdx.x * 256 + t;
    int e = (int)out[OFF_IND + tok];
    int p = atomicAdd(&lh[e], 1);
    __syncthreads();
    for (int i = t; i < N_EMBED; i += 256) {
        int c = lh[i];
        if (c) lbase[i] = atomicAdd(&cursor_i[i], c);
    }
    __syncthreads();
    int pos = lbase[e] + p;
    sorted[pos] = tok;
    scode[pos] = e;
}

__global__ __launch_bounds__(256) void vq_sum(
    const float* __restrict__ x, const int* __restrict__ sorted,
    const int* __restrict__ scode, float* __restrict__ es)
{
    __shared__ int ltok[SUM_TPB];
    __shared__ int lcode[SUM_TPB];
    const int t = threadIdx.x;
    const int base = blockIdx.x * SUM_TPB;
    if (t < SUM_TPB) {
        ltok[t]  = sorted[base + t];
        lcode[t] = scode[base + t];
    }
    __syncthreads();

    const int w = t >> 6, d = t & 63;
    const int i0 = w * (SUM_TPB / 4);
    int   cur = lcode[i0];
    float acc = 0.f;
#pragma unroll 4
    for (int i = i0; i < i0 + SUM_TPB / 4; ++i) {
        int e = lcode[i];
        if (e != cur) {
            atomicAdd(&es[(size_t)cur * DIM + d], acc);
            acc = 0.f;
            cur = e;
        }
        acc += x[(size_t)ltok[i] * DIM + d];
    }
    atomicAdd(&es[(size_t)cur * DIM + d], acc);
}

__global__ __launch_bounds__(256) void vq_final2(
    const float* __restrict__ embed_avg, const float* __restrict__ es,
    const float* __restrict__ n_val, float* __restrict__ out)
{
    int i = blockIdx.x * 256 + threadIdx.x;
    int e = i & 1023, d = i >> 10;
    float nea = embed_avg[i] * DECAYF + OMDF * es[(size_t)e * DIM + d];
    out[OFF_NEA + i] = nea;
    float ncs = out[OFF_NCS + e];
    float nsum = *n_val;
    float cs = (ncs + EPSF) / (nsum + (float)N_EMBED * EPSF) * nsum;
    out[OFF_NE + i] = nea / cs;
}

extern "C" void kernel_launch(void* const* d_in, const int* in_sizes, int n_in,
                              void* d_out, int out_size, void* d_ws, size_t ws_size,
                              hipStream_t stream)
{
    const float* x            = (const float*)d_in[0];
    const float* embed        = (const float*)d_in[1];
    const float* cluster_size = (const float*)d_in[2];
    const float* embed_avg    = (const float*)d_in[3];
    float* out = (float*)d_out;
    float* ws  = (float*)d_ws;

    float* diff_sum = ws + WS_DIFF;
    float* n_val    = ws + WS_NVAL;
    float* es       = ws + WS_ES;
    float* embedT   = ws + WS_ET;
    float* cnorm    = ws + WS_CNORM;
    int*   iws      = (int*)(ws + WS_IWS);
    int*   cnt_i    = iws;
    int*   cursor_i = iws + 2048;
    int*   sorted   = iws + 3072;
    int*   scode    = sorted + N_TOKENS;
    int*   nflag    = scode + N_TOKENS;
    int*   flaglist = nflag + 16;                       // 16-pad keeps bf arrays 16B-aligned
    unsigned short* eh_g = (unsigned short*)(flaglist + N_TOKENS);
    unsigned short* el_g = eh_g + N_EMBED * DIM;

    vq_prep<<<261, 256, 0, stream>>>(embed, embedT, cnorm, diff_sum, cnt_i, nflag, eh_g, el_g);
    vq_main<<<N_TOKENS / TOK_TILE, 256, 0, stream>>>(x, embedT, eh_g, el_g, cnorm, out,
                                                     diff_sum, cnt_i, nflag, flaglist);
    vq_fallback<<<FB_BLOCKS, 256, 0, stream>>>(x, embedT, cnorm, out,
                                               diff_sum, cnt_i, nflag, flaglist);
    vq_start<<<1, 1024, 0, stream>>>(cnt_i, cursor_i, cluster_size, diff_sum, out, n_val);
    vq_sort<<<N_TOKENS / 256, 256, 0, stream>>>(out, cursor_i, sorted, scode, es);
    vq_sum<<<N_TOKENS / SUM_TPB, 256, 0, stream>>>(x, sorted, scode, es);
    vq_final2<<<256, 256, 0, stream>>>(embed_avg, es, n_val, out);
}

// Round 15
// 337.843 us; speedup vs baseline: 1.0672x; 1.0011x over previous
//
#include <hip/hip_runtime.h>

#define N_TOKENS 131072
#define DIM 64
#define N_EMBED 1024
#define DECAYF 0.99f
#define OMDF 0.01f
#define EPSF 1e-5f
#define SUM_TPB 128
#define TOK_TILE 128
#define CODE_CHUNK 128
#define NCHUNK (N_EMBED / CODE_CHUNK)
#define MARGIN 0.004f         // 8x the ~5e-4 bf16x3 score error bound
#define FB_BATCH 16
#define FB_BLOCKS 128

// Output layout (floats), reference return order
#define OFF_QST  ((size_t)0)
#define OFF_DIFF ((size_t)8388608)
#define OFF_IND  ((size_t)8388609)
#define OFF_NE   ((size_t)8519681)
#define OFF_NCS  ((size_t)8585217)
#define OFF_NEA  ((size_t)8586241)

// ws: floats f[0] diff_sum, f[1] n_val, f[1026..) es, f[66562..) embedT,
// f[132098..) cnorm; ints at f-idx 133632: cnt_i@0, cursor_i@2048,
// sorted@3072, scode, nflag[0]/done[1] (16-pad), flaglist, bf16 eh_g/el_g.
#define WS_DIFF   0
#define WS_NVAL   1
#define WS_ES     1026
#define WS_ET     66562
#define WS_CNORM  132098
#define WS_IWS    133632

typedef short bfrag8 __attribute__((ext_vector_type(8)));   // 8 bf16 (4 VGPR)
typedef float f32x4  __attribute__((ext_vector_type(4)));

__device__ inline unsigned short f2bf(float f) {
    unsigned u = __float_as_uint(f);
    u += 0x7FFFu + ((u >> 16) & 1u);                        // round-to-nearest-even
    return (unsigned short)(u >> 16);
}
__device__ inline float bf2f(unsigned short h) {
    return __uint_as_float(((unsigned)h) << 16);
}
// 8 fp32 -> packed hi/lo bf16 fragments (in registers)
__device__ inline void cvt8(float4 f0, float4 f1, bfrag8* hi, bfrag8* lo) {
    union { bfrag8 v; unsigned u[4]; } H, L;
    unsigned short h0=f2bf(f0.x), h1=f2bf(f0.y), h2=f2bf(f0.z), h3=f2bf(f0.w);
    unsigned short h4=f2bf(f1.x), h5=f2bf(f1.y), h6=f2bf(f1.z), h7=f2bf(f1.w);
    H.u[0]=(unsigned)h0|((unsigned)h1<<16); H.u[1]=(unsigned)h2|((unsigned)h3<<16);
    H.u[2]=(unsigned)h4|((unsigned)h5<<16); H.u[3]=(unsigned)h6|((unsigned)h7<<16);
    L.u[0]=(unsigned)f2bf(f0.x-bf2f(h0))|((unsigned)f2bf(f0.y-bf2f(h1))<<16);
    L.u[1]=(unsigned)f2bf(f0.z-bf2f(h2))|((unsigned)f2bf(f0.w-bf2f(h3))<<16);
    L.u[2]=(unsigned)f2bf(f1.x-bf2f(h4))|((unsigned)f2bf(f1.y-bf2f(h5))<<16);
    L.u[3]=(unsigned)f2bf(f1.z-bf2f(h6))|((unsigned)f2bf(f1.w-bf2f(h7))<<16);
    *hi = H.v; *lo = L.v;
}

__global__ __launch_bounds__(256) void vq_prep(
    const float* __restrict__ embed, float* __restrict__ embedT,
    float* __restrict__ cnorm, float* __restrict__ diff_sum,
    int* __restrict__ cnt_i, int* __restrict__ nflag,
    unsigned short* __restrict__ eh_g, unsigned short* __restrict__ el_g)
{
    const int b = blockIdx.x, t = threadIdx.x;
    if (b < 256) {
        int i = b * 256 + t;
        int d = i >> 10, e = i & 1023;
        float v = embed[i];
        embedT[e * DIM + d] = v;
        unsigned short h = f2bf(v);
        eh_g[e * DIM + d] = h;
        el_g[e * DIM + d] = f2bf(v - bf2f(h));
    } else if (b < 260) {
        int e = (b - 256) * 256 + t;
        float s = 0.f;
#pragma unroll
        for (int d = 0; d < DIM; ++d) {
            float v = embed[d * N_EMBED + e];
            s = fmaf(v, v, s);
        }
        cnorm[e] = s;
    } else {
        for (int i = t; i < N_EMBED; i += 256) cnt_i[i] = 0;
        if (t < 2) diff_sum[t] = 0.f;
        if (t < 2) nflag[t] = 0;           // nflag[0]=count, nflag[1]=done-counter
    }
}

// bf16x3 MFMA distance GEMM, no LDS in the main loop.
// r15: DEPTH-3 B prefetch queue (r14's one-slot gave 58cyc cover vs ~250cyc
// L2 latency -> ~100us stall, MfmaUtil 13%). q0..q2 named pairs; rotation is
// SSA-renamed by the compiler (no alloca). Dependency distance = 36 MFMAs.
__global__ __launch_bounds__(256, 1) void vq_main(
    const float* __restrict__ x, const float* __restrict__ embedT,
    const unsigned short* __restrict__ eh_g, const unsigned short* __restrict__ el_g,
    const float* __restrict__ cnorm, float* __restrict__ out,
    float* __restrict__ diff_sum, int* __restrict__ cnt_i,
    int* __restrict__ nflag, int* __restrict__ flaglist)
{
    __shared__ float red_b[256];
    __shared__ float red_s[256];
    __shared__ int   red_i[256];
    __shared__ int   bi_l[TOK_TILE];
    __shared__ int   lhist[N_EMBED];            // ~7.7 KB total

    const int t = threadIdx.x;
    const int w = t >> 6, lane = t & 63;
    const int wr = w >> 1, wc = w & 1;
    const int col = lane & 15, q = lane >> 4;
    const int qk = q * 8;

    for (int i = t; i < N_EMBED; i += 256) lhist[i] = 0;

    // A-frags: 16 named bfrag8 (alloca lesson from r10)
    bfrag8 ah0_0, ah0_1, ah0_2, ah0_3, ah1_0, ah1_1, ah1_2, ah1_3;
    bfrag8 al0_0, al0_1, al0_2, al0_3, al1_0, al1_1, al1_2, al1_3;
    {
        const float* xrb = x + ((size_t)blockIdx.x * TOK_TILE + wr * 64 + col) * DIM;
#define MAKE_A(KT, I, AH, AL) { \
        const float* p_ = xrb + (I) * 16 * DIM + (KT) * 32 + qk; \
        cvt8(*(const float4*)p_, *(const float4*)(p_ + 4), &AH, &AL); }
        MAKE_A(0,0,ah0_0,al0_0) MAKE_A(0,1,ah0_1,al0_1)
        MAKE_A(0,2,ah0_2,al0_2) MAKE_A(0,3,ah0_3,al0_3)
        MAKE_A(1,0,ah1_0,al1_0) MAKE_A(1,1,ah1_1,al1_1)
        MAKE_A(1,2,ah1_2,al1_2) MAKE_A(1,3,ah1_3,al1_3)
#undef MAKE_A
    }

    float best[16], sec[16];
    int   bidx[16];
#pragma unroll
    for (int s = 0; s < 16; ++s) { best[s] = -3.4e38f; sec[s] = -3.4e38f; bidx[s] = 0; }

#define LOADB(G, BH, BL) { \
    int gg_ = (G) > 63 ? 63 : (G); \
    int cb_ = (((gg_ >> 3) * 128 + wc * 64 + (gg_ & 3) * 16 + col) << 6) \
              + ((gg_ >> 2) & 1) * 32 + qk; \
    BH = *(const bfrag8*)(eh_g + cb_); \
    BL = *(const bfrag8*)(el_g + cb_); }

    // depth-3 prefetch queue (slot g = chunk*8 + s; kt = s>>2, j = s&3)
    bfrag8 q0h, q0l, q1h, q1l, q2h, q2l;
    LOADB(0, q0h, q0l)
    LOADB(1, q1h, q1l)
    LOADB(2, q2h, q2l)

#define MM3(AH,AL,BH,BL,J) \
    acc[0][J]=__builtin_amdgcn_mfma_f32_16x16x32_bf16(AH##_0,BH,acc[0][J],0,0,0); \
    acc[1][J]=__builtin_amdgcn_mfma_f32_16x16x32_bf16(AH##_1,BH,acc[1][J],0,0,0); \
    acc[2][J]=__builtin_amdgcn_mfma_f32_16x16x32_bf16(AH##_2,BH,acc[2][J],0,0,0); \
    acc[3][J]=__builtin_amdgcn_mfma_f32_16x16x32_bf16(AH##_3,BH,acc[3][J],0,0,0); \
    acc[0][J]=__builtin_amdgcn_mfma_f32_16x16x32_bf16(AH##_0,BL,acc[0][J],0,0,0); \
    acc[1][J]=__builtin_amdgcn_mfma_f32_16x16x32_bf16(AH##_1,BL,acc[1][J],0,0,0); \
    acc[2][J]=__builtin_amdgcn_mfma_f32_16x16x32_bf16(AH##_2,BL,acc[2][J],0,0,0); \
    acc[3][J]=__builtin_amdgcn_mfma_f32_16x16x32_bf16(AH##_3,BL,acc[3][J],0,0,0); \
    acc[0][J]=__builtin_amdgcn_mfma_f32_16x16x32_bf16(AL##_0,BH,acc[0][J],0,0,0); \
    acc[1][J]=__builtin_amdgcn_mfma_f32_16x16x32_bf16(AL##_1,BH,acc[1][J],0,0,0); \
    acc[2][J]=__builtin_amdgcn_mfma_f32_16x16x32_bf16(AL##_2,BH,acc[2][J],0,0,0); \
    acc[3][J]=__builtin_amdgcn_mfma_f32_16x16x32_bf16(AL##_3,BH,acc[3][J],0,0,0);

#define SLOT(KT, S) { \
    bfrag8 bh_ = q0h, bl_ = q0l; \
    q0h = q1h; q0l = q1l; q1h = q2h; q1l = q2l; \
    LOADB(g0 + (S) + 3, q2h, q2l) \
    MM3(ah##KT, al##KT, bh_, bl_, ((S) & 3)) }

#pragma unroll 1
    for (int chunk = 0; chunk < NCHUNK; ++chunk) {
        const int g0 = chunk * 8;
        f32x4 acc[4][4];
#pragma unroll
        for (int i = 0; i < 4; ++i)
#pragma unroll
            for (int j = 0; j < 4; ++j) acc[i][j] = (f32x4){0.f, 0.f, 0.f, 0.f};

        SLOT(0,0) SLOT(0,1) SLOT(0,2) SLOT(0,3)
        SLOT(1,4) SLOT(1,5) SLOT(1,6) SLOT(1,7)

        // running best/second (ties land inside MARGIN -> flagged -> exact)
#pragma unroll
        for (int j = 0; j < 4; ++j) {
            int code = chunk * CODE_CHUNK + wc * 64 + j * 16 + col;
            float cnj = 0.5f * cnorm[code];
#pragma unroll
            for (int i = 0; i < 4; ++i) {
#pragma unroll
                for (int r = 0; r < 4; ++r) {
                    float sc = acc[i][j][r] - cnj;
                    int s = i * 4 + r;
                    sec[s] = fmaxf(sec[s], fminf(best[s], sc));
                    bidx[s] = (sc > best[s]) ? code : bidx[s];
                    best[s] = fmaxf(best[s], sc);
                }
            }
        }
    }
#undef SLOT
#undef MM3
#undef LOADB

    // intra-quad butterfly over the 16 code-columns
#pragma unroll
    for (int s = 0; s < 16; ++s) {
#pragma unroll
        for (int m = 1; m < 16; m <<= 1) {
            float b2 = __shfl_xor(best[s], m, 64);
            float s2 = __shfl_xor(sec[s],  m, 64);
            int   i2 = __shfl_xor(bidx[s], m, 64);
            float mn = fminf(best[s], b2);
            sec[s]  = fmaxf(fmaxf(sec[s], s2), mn);
            bidx[s] = (b2 > best[s]) ? i2 : bidx[s];
            best[s] = fmaxf(best[s], b2);
        }
    }
    if (col == 0) {
#pragma unroll
        for (int i = 0; i < 4; ++i)
#pragma unroll
            for (int r = 0; r < 4; ++r) {
                int tl = wr * 64 + i * 16 + q * 4 + r;
                red_b[wc * 128 + tl] = best[i * 4 + r];
                red_s[wc * 128 + tl] = sec[i * 4 + r];
                red_i[wc * 128 + tl] = bidx[i * 4 + r];
            }
    }
    __syncthreads();

    if (t < TOK_TILE) {
        float b0 = red_b[t], b1 = red_b[128 + t];
        float s0 = red_s[t], s1 = red_s[128 + t];
        int   i0 = red_i[t], i1 = red_i[128 + t];
        float B = fmaxf(b0, b1);
        float S = fmaxf(fmaxf(s0, s1), fminf(b0, b1));
        int idx = (b1 > b0) ? i1 : i0;
        bool flag = (B - S) < MARGIN;
        bi_l[t] = idx | (flag ? 0x10000 : 0);
        int token = blockIdx.x * TOK_TILE + t;
        out[OFF_IND + token] = (float)idx;             // fallback overwrites flagged
        if (flag) { int p = atomicAdd(&nflag[0], 1); flaglist[p] = token; }
        else atomicAdd(&lhist[idx], 1);
    }
    __syncthreads();

    // quantize + diff for unflagged tokens
    float ds = 0.f;
    {
        const float4* et4 = (const float4*)embedT;
        const float4* xs4 = (const float4*)(x + (size_t)blockIdx.x * TOK_TILE * DIM);
        float4* qst = (float4*)(out + OFF_QST + (size_t)blockIdx.x * TOK_TILE * DIM);
#pragma unroll
        for (int j = 0; j < 8; ++j) {
            int g = j * 256 + t;
            int tok = g >> 4, f = g & 15;
            int bir = bi_l[tok];
            int bi = bir & 0xFFFF;
            float4 qv = et4[bi * 16 + f];
            float4 xv = xs4[g];
            if (!(bir & 0x10000)) {
                qst[g] = qv;
                float ex = qv.x - xv.x, ey = qv.y - xv.y;
                float ez = qv.z - xv.z, ew = qv.w - xv.w;
                ds = fmaf(ex, ex, ds); ds = fmaf(ey, ey, ds);
                ds = fmaf(ez, ez, ds); ds = fmaf(ew, ew, ds);
            }
        }
    }
#pragma unroll
    for (int o = 32; o > 0; o >>= 1) ds += __shfl_down(ds, o, 64);
    if (lane == 0) atomicAdd(diff_sum, ds);

    for (int i = t; i < N_EMBED; i += 256) {
        int cv = lhist[i];
        if (cv) atomicAdd(&cnt_i[i], cv);
    }
}

// Exact fp32 recompute for flagged tokens + (last block) merged prefix-scan /
// EMA / n / diff finalize (former vq_start; must run after all cnt_i updates,
// which include fallback's own -> done-counter last-block pattern).
__global__ __launch_bounds__(256) void vq_fallback(
    const float* __restrict__ x, const float* __restrict__ embedT,
    const float* __restrict__ cnorm, float* __restrict__ out,
    float* __restrict__ diff_sum, int* __restrict__ cnt_i,
    int* __restrict__ nflag, const int* __restrict__ flaglist,
    int* __restrict__ cursor_i, const float* __restrict__ cluster_size,
    float* __restrict__ n_val)
{
    __shared__ float xr[FB_BATCH][68];
    __shared__ float ec[128][68];
    __shared__ float rd[FB_BATCH][16];
    __shared__ int   ri[FB_BATCH][16];
    __shared__ int   win[FB_BATCH];
    __shared__ int   toks[FB_BATCH];
    __shared__ int   lastflag;
    __shared__ int   wtot[4];
    __shared__ float wns[4];

    const int t = threadIdx.x;
    const int nf = nflag[0];

    for (int base = blockIdx.x * FB_BATCH; base < nf; base += gridDim.x * FB_BATCH) {
        __syncthreads();
        if (t < FB_BATCH) toks[t] = (base + t < nf) ? flaglist[base + t] : -1;
        __syncthreads();
        for (int i = t; i < FB_BATCH * 64; i += 256) {
            int tk = i >> 6, d = i & 63;
            int token = toks[tk];
            xr[tk][d] = (token >= 0) ? x[(size_t)token * DIM + d] : 0.f;
        }
        float bd = 3.4e38f; int be = 0;
        const int tok = t >> 4, l16 = t & 15;
        for (int ch = 0; ch < 8; ++ch) {
            __syncthreads();
            {
                const float4* src = (const float4*)(embedT + (size_t)ch * 128 * DIM);
                for (int i = t; i < 2048; i += 256) {
                    int row = i >> 4, kp = (i & 15) << 2;
                    *(float4*)(&ec[row][kp]) = src[i];
                }
            }
            __syncthreads();
#pragma unroll 1
            for (int cc = 0; cc < 8; ++cc) {
                int lc = l16 + cc * 16;
                float d0 = 0.f, d1 = 0.f, d2 = 0.f, d3 = 0.f;
#pragma unroll
                for (int k4 = 0; k4 < 16; ++k4) {
                    float4 a = *(const float4*)(&xr[tok][k4 << 2]);
                    float4 b = *(const float4*)(&ec[lc][k4 << 2]);
                    d0 = fmaf(a.x, b.x, d0); d1 = fmaf(a.y, b.y, d1);
                    d2 = fmaf(a.z, b.z, d2); d3 = fmaf(a.w, b.w, d3);
                }
                int ge = ch * 128 + lc;
                float dist = fmaf(-2.f, (d0 + d1) + (d2 + d3), cnorm[ge]);
                if (dist < bd) { bd = dist; be = ge; }
            }
        }
        rd[tok][l16] = bd; ri[tok][l16] = be;
        __syncthreads();
        if (t < FB_BATCH) {
            float d0 = rd[t][0]; int e0 = ri[t][0];
#pragma unroll
            for (int i = 1; i < 16; ++i) {
                float di = rd[t][i]; int ei = ri[t][i];
                if (di < d0 || (di == d0 && ei < e0)) { d0 = di; e0 = ei; }
            }
            win[t] = e0;
            int token = toks[t];
            if (token >= 0) {
                out[OFF_IND + token] = (float)e0;
                atomicAdd(&cnt_i[e0], 1);
            }
        }
        __syncthreads();
        float ds = 0.f;
        for (int i = t; i < FB_BATCH * 64; i += 256) {
            int tk = i >> 6, d = i & 63;
            int token = toks[tk];
            if (token >= 0) {
                float qv = embedT[(size_t)win[tk] * DIM + d];
                out[OFF_QST + (size_t)token * DIM + d] = qv;
                float e = qv - xr[tk][d];
                ds = fmaf(e, e, ds);
            }
        }
#pragma unroll
        for (int o = 32; o > 0; o >>= 1) ds += __shfl_down(ds, o, 64);
        if ((t & 63) == 0 && ds != 0.f) atomicAdd(diff_sum, ds);
    }

    // ---- last-block: merged vq_start (prefix scan + EMA + n + diff) ----
    __threadfence();                                   // release our updates
    if (t == 0) lastflag = (atomicAdd(&nflag[1], 1) == FB_BLOCKS - 1);
    __syncthreads();
    if (!lastflag) return;
    __threadfence();                                   // acquire others' updates

    const int lane = t & 63, w = t >> 6;
    int base4 = t * 4;
    int c0 = cnt_i[base4], c1 = cnt_i[base4 + 1];
    int c2 = cnt_i[base4 + 2], c3 = cnt_i[base4 + 3];
    int s1 = c0 + c1, s2 = s1 + c2, tot = s2 + c3;

    int inc = tot;
#pragma unroll
    for (int o = 1; o < 64; o <<= 1) {
        int v = __shfl_up(inc, o, 64);
        if (lane >= o) inc += v;
    }
    float ncs0 = cluster_size[base4]     * DECAYF + OMDF * (float)c0;
    float ncs1 = cluster_size[base4 + 1] * DECAYF + OMDF * (float)c1;
    float ncs2 = cluster_size[base4 + 2] * DECAYF + OMDF * (float)c2;
    float ncs3 = cluster_size[base4 + 3] * DECAYF + OMDF * (float)c3;
    out[OFF_NCS + base4]     = ncs0;
    out[OFF_NCS + base4 + 1] = ncs1;
    out[OFF_NCS + base4 + 2] = ncs2;
    out[OFF_NCS + base4 + 3] = ncs3;
    float ns = (ncs0 + ncs1) + (ncs2 + ncs3);
#pragma unroll
    for (int o = 32; o > 0; o >>= 1) ns += __shfl_down(ns, o, 64);
    if (lane == 63) wtot[w] = inc;
    if (lane == 0)  wns[w] = ns;
    __syncthreads();
    int woff = 0;
#pragma unroll
    for (int i = 0; i < 4; ++i) woff += (i < w) ? wtot[i] : 0;
    int eb = woff + inc - tot;                         // exclusive base for base4
    cursor_i[base4]     = eb;
    cursor_i[base4 + 1] = eb + c0;
    cursor_i[base4 + 2] = eb + s1;
    cursor_i[base4 + 3] = eb + s2;
    if (t == 0) {
        float nsum = (wns[0] + wns[1]) + (wns[2] + wns[3]);
        *n_val = nsum;
        out[OFF_DIFF] = *diff_sum / (float)((size_t)N_TOKENS * DIM);
    }
}

__global__ __launch_bounds__(256) void vq_sort(
    const float* __restrict__ out, int* __restrict__ cursor_i,
    int* __restrict__ sorted, int* __restrict__ scode,
    float* __restrict__ es)
{
    __shared__ int lh[N_EMBED];
    __shared__ int lbase[N_EMBED];
    int t = threadIdx.x;
    if (blockIdx.x < 256) es[blockIdx.x * 256 + t] = 0.f;
    for (int i = t; i < N_EMBED; i += 256) lh[i] = 0;
    __syncthreads();
    int tok = blockIdx.x * 256 + t;
    int e = (int)out[OFF_IND + tok];
    int p = atomicAdd(&lh[e], 1);
    __syncthreads();
    for (int i = t; i < N_EMBED; i += 256) {
        int c = lh[i];
        if (c) lbase[i] = atomicAdd(&cursor_i[i], c);
    }
    __syncthreads();
    int pos = lbase[e] + p;
    sorted[pos] = tok;
    scode[pos] = e;
}

__global__ __launch_bounds__(256) void vq_sum(
    const float* __restrict__ x, const int* __restrict__ sorted,
    const int* __restrict__ scode, float* __restrict__ es)
{
    __shared__ int ltok[SUM_TPB];
    __shared__ int lcode[SUM_TPB];
    const int t = threadIdx.x;
    const int base = blockIdx.x * SUM_TPB;
    if (t < SUM_TPB) {
        ltok[t]  = sorted[base + t];
        lcode[t] = scode[base + t];
    }
    __syncthreads();

    const int w = t >> 6, d = t & 63;
    const int i0 = w * (SUM_TPB / 4);
    int   cur = lcode[i0];
    float acc = 0.f;
#pragma unroll 4
    for (int i = i0; i < i0 + SUM_TPB / 4; ++i) {
        int e = lcode[i];
        if (e != cur) {
            atomicAdd(&es[(size_t)cur * DIM + d], acc);
            acc = 0.f;
            cur = e;
        }
        acc += x[(size_t)ltok[i] * DIM + d];
    }
    atomicAdd(&es[(size_t)cur * DIM + d], acc);
}

__global__ __launch_bounds__(256) void vq_final2(
    const float* __restrict__ embed_avg, const float* __restrict__ es,
    const float* __restrict__ n_val, float* __restrict__ out)
{
    int i = blockIdx.x * 256 + threadIdx.x;
    int e = i & 1023, d = i >> 10;
    float nea = embed_avg[i] * DECAYF + OMDF * es[(size_t)e * DIM + d];
    out[OFF_NEA + i] = nea;
    float ncs = out[OFF_NCS + e];
    float nsum = *n_val;
    float cs = (ncs + EPSF) / (nsum + (float)N_EMBED * EPSF) * nsum;
    out[OFF_NE + i] = nea / cs;
}

extern "C" void kernel_launch(void* const* d_in, const int* in_sizes, int n_in,
                              void* d_out, int out_size, void* d_ws, size_t ws_size,
                              hipStream_t stream)
{
    const float* x            = (const float*)d_in[0];
    const float* embed        = (const float*)d_in[1];
    const float* cluster_size = (const float*)d_in[2];
    const float* embed_avg    = (const float*)d_in[3];
    float* out = (float*)d_out;
    float* ws  = (float*)d_ws;

    float* diff_sum = ws + WS_DIFF;
    float* n_val    = ws + WS_NVAL;
    float* es       = ws + WS_ES;
    float* embedT   = ws + WS_ET;
    float* cnorm    = ws + WS_CNORM;
    int*   iws      = (int*)(ws + WS_IWS);
    int*   cnt_i    = iws;
    int*   cursor_i = iws + 2048;
    int*   sorted   = iws + 3072;
    int*   scode    = sorted + N_TOKENS;
    int*   nflag    = scode + N_TOKENS;                 // [0]=count, [1]=done
    int*   flaglist = nflag + 16;                       // 16-pad keeps bf arrays aligned
    unsigned short* eh_g = (unsigned short*)(flaglist + N_TOKENS);
    unsigned short* el_g = eh_g + N_EMBED * DIM;

    vq_prep<<<261, 256, 0, stream>>>(embed, embedT, cnorm, diff_sum, cnt_i, nflag, eh_g, el_g);
    vq_main<<<N_TOKENS / TOK_TILE, 256, 0, stream>>>(x, embedT, eh_g, el_g, cnorm, out,
                                                     diff_sum, cnt_i, nflag, flaglist);
    vq_fallback<<<FB_BLOCKS, 256, 0, stream>>>(x, embedT, cnorm, out, diff_sum, cnt_i,
                                               nflag, flaglist, cursor_i, cluster_size, n_val);
    vq_sort<<<N_TOKENS / 256, 256, 0, stream>>>(out, cursor_i, sorted, scode, es);
    vq_sum<<<N_TOKENS / SUM_TPB, 256, 0, stream>>>(x, sorted, scode, es);
    vq_final2<<<256, 256, 0, stream>>>(embed_avg, es, n_val, out);
}